// Round 9
// baseline (351.724 us; speedup 1.0000x reference)
//
#include <hip/hip_runtime.h>
#include <math.h>

#define WIN 11
#define PAD 5

typedef float v2f __attribute__((ext_vector_type(2)));

struct GW { float g[WIN]; };

template<int N> struct IC { static constexpr int value = N; };

// ---------------------------------------------------------------------------
// Wave-autonomous SSIM tile, DOUBLE-ROW STATIC-RING, SCALAR-ACCUMULATOR.
// Compiler fact (3x confirmed: R1, R7, R8): loop-carried ext_vector ARRAYS
// are demoted to scratch (WRITE_SIZE 200MB, dur +65%) no matter how static
// the indexing; loop-carried SCALAR float arrays live in VGPRs (R0/R2/R4/R5).
// So: accumulators are float vMp/vSp/vMq/vSq[12]; v2f only for TRANSIENT
// H-conv values (proven safe R3/R5). All state in ONE function scope; the
// step is a generic lambda taking IC<U> so every ring index / tap weight is
// a compile-time literal (no macros - R7 trap; no array-by-ref - R8 risk).
// Structure (one step = image rows 2d, 2d+1):
//   - branchless 2-row-ahead prefetch (R5: uniform vmcnt)
//   - LDS float4 (p0,q0,p1,q1): 11 ds_read_b128 + 2 writes per 2 rows =
//     DS instruction count HALVED vs per-row float2 (R7 data: conflicts
//     halved too); per-CU model says issue/DS-queue contention ~ total
//     instr count, the only lever that has tracked duration (R0-R8).
//   - packed H-conv of both rows per tap (6 pk-ops) - transient v2f only
//   - scalar V-conv ring: 12 slots, slot s holds output o == s (mod 12);
//     step d: row 2d taps w0=(2d-s) mod 12 (if <=10), row 2d+1 taps w0+1
//     (if <=10); slots (2d+2)%12, (2d+3)%12 emit outputs 2d-10, 2d-9, zero.
//   - 21 steps = rows 0..41 exactly: 3 unrolled blocks of 6 + 3-step tail;
//     U = d mod 6 literal at every call site.
// Tripwire: WRITE_SIZE ~24.8MB / FETCH ~78MB; any growth = scratch = revert.
// EMIT: L0 pools rows (2d-1, 2d) into L1 at steps with 6 <= 2d <= 36.
// ---------------------------------------------------------------------------
template<bool EMIT>
__device__ __forceinline__ float ssim_wave_tile(
    const float* __restrict__ p1, const float* __restrict__ p2,
    int W, int X0, int Y0, const GW& gw, float4* __restrict__ rb,
    float* __restrict__ o1a, float* __restrict__ o1b, int Wout)
{
    const int lane = threadIdx.x & 63;
    const int gx = X0 + lane;
    const bool cval = gx < W;                              // false only for L4 lanes 32+
    const int hx   = (lane < 5) ? (X0 - 5 + lane) : (X0 + 59 + lane);
    const bool hval = (lane < 10) && ((unsigned)hx < (unsigned)W);
    const int hpos = (lane < 5) ? lane : (64 + lane);      // 0..4 | 69..73
    const int cpos = 5 + lane;
    const int gxc = cval ? gx : 0;                         // clamped main col
    const int hxc = hval ? hx : gxc;                       // masked halo -> own col
    const int wpos = (lane < 10) ? hpos : cpos;            // branchless halo write

    // loop-carried state: SCALARS ONLY (see header comment)
    float vMp[12], vSp[12], vMq[12], vSq[12];
#pragma unroll
    for (int k = 0; k < 12; ++k) { vMp[k] = 0.f; vSp[k] = 0.f; vMq[k] = 0.f; vSq[k] = 0.f; }

    float part = 0.f, pprev = 0.f, qprev = 0.f;
    float c0a, c0b, c0ah, c0bh, c1a, c1b, c1ah, c1bh;      // current rows 2d, 2d+1

    // BRANCHLESS per-row load: 4 unconditional loads, results zero-selected.
    auto LOAD = [&](int t, float& oa, float& ob, float& oah, float& obh) {
        int y = Y0 - PAD + t;
        bool yin = (unsigned)y < (unsigned)W;
        const float* r1 = p1 + (size_t)(yin ? y : 0) * W;
        const float* r2 = p2 + (size_t)(yin ? y : 0) * W;
        float va = r1[gxc], vb = r2[gxc];
        float wa = r1[hxc], wb = r2[hxc];
        bool cv = yin && cval;
        bool hv = yin && hval;
        oa  = cv ? va : 0.f;
        ob  = cv ? vb : 0.f;
        oah = hv ? wa : 0.f;
        obh = hv ? wb : 0.f;
    };

    auto EMIT1 = [&](float Mp, float Mq, float Sp_, float Sq_, int o) {
        if ((unsigned)o < 32u) {
            bool yok = (unsigned)(Y0 + o) < (unsigned)W;   // false only for L4 tail
            const float C1v = 1e-4f, C2v = 9e-4f;
            float A = Mp * Mp, B = Mq * Mq;
            float ABp = A + B, ABm = A - B;
            float SSp = Sp_ + Sq_, SSm = Sp_ - Sq_;
            float n1 = fmaf(0.5f, ABm, C1v);         // 2*m12 + C1
            float n2 = fmaf(0.5f, SSm - ABm, C2v);   // 2*s12 + C2
            float e1 = fmaf(0.5f, ABp, C1v);         // m1^2+m2^2 + C1
            float e2 = fmaf(0.5f, SSp - ABp, C2v);   // s1+s2 + C2
            float val = (n1 * n2) * __builtin_amdgcn_rcpf(e1 * e2);
            part += (cval && yok) ? val : 0.f;
        }
    };

    LOAD(0, c0a, c0b, c0ah, c0bh);
    LOAD(1, c1a, c1b, c1ah, c1bh);

    auto step = [&](auto Uc, int d) {
        constexpr int U = decltype(Uc)::value;             // U == d mod 6, literal

        // 1) prefetch next double-row (rows 2d+2, 2d+3), consumed next step
        float n0, n1, n2, n3, n4, n5, n6, n7;
        LOAD(2 * d + 2, n0, n1, n2, n3);
        LOAD(2 * d + 3, n4, n5, n6, n7);

        // 2) LDS write rows (2d, 2d+1) packed as float4
        float p0  = c0a + c0b,  q0  = c0a - c0b;
        float ph0 = c0ah + c0bh, qh0 = c0ah - c0bh;
        float p1r = c1a + c1b,  q1r = c1a - c1b;
        float ph1 = c1ah + c1bh, qh1 = c1ah - c1bh;
        rb[cpos] = make_float4(p0, q0, p1r, q1r);
        rb[wpos] = (lane < 10) ? make_float4(ph0, qh0, ph1, qh1)
                               : make_float4(p0, q0, p1r, q1r);
        __builtin_amdgcn_wave_barrier();   // writes -> reads (cross-lane RAW)

        // 3) H-conv of both rows from one b128 read per tap (transient v2f)
        v2f hM0 = {0.f, 0.f}, hS0 = {0.f, 0.f};
        v2f hM1 = {0.f, 0.f}, hS1 = {0.f, 0.f};
#pragma unroll
        for (int j = 0; j < WIN; ++j) {
            float4 vv = rb[lane + j];
            v2f v0 = { vv.x, vv.y }, v1 = { vv.z, vv.w };
            v2f g2 = { gw.g[j], gw.g[j] };
            hM0 = __builtin_elementwise_fma(g2, v0, hM0);
            hS0 = __builtin_elementwise_fma(g2, v0 * v0, hS0);
            hM1 = __builtin_elementwise_fma(g2, v1, hM1);
            hS1 = __builtin_elementwise_fma(g2, v1 * v1, hS1);
        }
        __builtin_amdgcn_wave_barrier();   // reads -> next step's writes (WAR)
        float hp0 = hM0.x, hq0 = hM0.y, hpp0 = hS0.x, hqq0 = hS0.y;
        float hp1 = hM1.x, hq1 = hM1.y, hpp1 = hS1.x, hqq1 = hS1.y;

        // 4) V-conv static ring, SCALAR accumulators; weights fold at compile time
#pragma unroll
        for (int s = 0; s < 12; ++s) {
            constexpr int SS = 0;  (void)SS;
            const int w0v = ((2 * U - s) % 12 + 12) % 12;  // compile-time per (U,s)
            if (w0v <= 10) {
                float g = gw.g[w0v];
                vMp[s] = fmaf(g, hp0,  vMp[s]);
                vSp[s] = fmaf(g, hpp0, vSp[s]);
                vMq[s] = fmaf(g, hq0,  vMq[s]);
                vSq[s] = fmaf(g, hqq0, vSq[s]);
            }
            const int w1v = (w0v + 1) % 12;
            if (w1v <= 10) {
                float g = gw.g[w1v];
                vMp[s] = fmaf(g, hp1,  vMp[s]);
                vSp[s] = fmaf(g, hpp1, vSp[s]);
                vMq[s] = fmaf(g, hq1,  vMq[s]);
                vSq[s] = fmaf(g, hqq1, vSq[s]);
            }
        }

        // 5) emit the two completed outputs (o = 2d-10, 2d-9), zero their slots
        {
            constexpr int s0 = (2 * U + 2) % 12;
            constexpr int s1 = (2 * U + 3) % 12;
            EMIT1(vMp[s0], vMq[s0], vSp[s0], vSq[s0], 2 * d - 10);
            EMIT1(vMp[s1], vMq[s1], vSp[s1], vSq[s1], 2 * d - 9);
            vMp[s0] = 0.f; vSp[s0] = 0.f; vMq[s0] = 0.f; vSq[s0] = 0.f;
            vMp[s1] = 0.f; vSp[s1] = 0.f; vMq[s1] = 0.f; vSq[s1] = 0.f;
        }

        // 6) L0 pooling of image rows (2d-1, 2d) -> L1
        if (EMIT) {
            int r_ = 2 * d;
            if (r_ >= 6 && r_ <= 36) {
                float sp_ = p0 + pprev, sq_ = q0 + qprev;
                float sp2 = sp_ + __shfl_down(sp_, 1, 64);
                float sq2 = sq_ + __shfl_down(sq_, 1, 64);
                if ((lane & 1) == 0) {
                    float P = sp2 * 0.25f, Q = sq2 * 0.25f;
                    int yo = d - 3;
                    size_t oo = (size_t)((Y0 >> 1) + yo) * Wout
                              + ((X0 >> 1) + (lane >> 1));
                    o1a[oo] = (P + Q) * 0.5f;
                    o1b[oo] = (P - Q) * 0.5f;
                }
            }
            pprev = p1r; qprev = q1r;
        }

        // 7) rotate prefetch regs (named scalars)
        c0a = n0; c0b = n1; c0ah = n2; c0bh = n3;
        c1a = n4; c1b = n5; c1ah = n6; c1bh = n7;

        // pin step boundary: no cross-step motion (R8 unroll-hoist trap)
        __builtin_amdgcn_sched_barrier(0);
    };

    // 21 double-steps (rows 0..41): 3 unrolled blocks of 6 + 3-step tail.
#pragma unroll 1
    for (int blk = 0; blk < 3; ++blk) {
        const int db = blk * 6;
        step(IC<0>{}, db + 0);
        step(IC<1>{}, db + 1);
        step(IC<2>{}, db + 2);
        step(IC<3>{}, db + 3);
        step(IC<4>{}, db + 4);
        step(IC<5>{}, db + 5);
    }
    step(IC<0>{}, 18);
    step(IC<1>{}, 19);
    step(IC<2>{}, 20);

    return part;
}

// ---- L0: 8x16 tiles (64x32) x 48 images = 6144 waves (1536 blocks); emits L1 ----
__global__ __launch_bounds__(256, 4) void ssim_l0_kernel(
    const float* __restrict__ i1, const float* __restrict__ i2,
    float* __restrict__ a1, float* __restrict__ b1,
    double* __restrict__ acc, GW gw)
{
    __shared__ float4 rbs[4][80];
    const int wid = threadIdx.x >> 6;
    const int w = blockIdx.x * 4 + wid;
    const int img = w >> 7;                 // 128 tiles per image
    const int tt = w & 127;
    const int tx = tt & 7, ty = tt >> 3;    // 8 cols x 16 rows
    const size_t off  = (size_t)img * 512 * 512;
    const size_t ooff = (size_t)img * 256 * 256;

    float part = ssim_wave_tile<true>(i1 + off, i2 + off, 512, tx * 64, ty * 32,
                                      gw, rbs[wid], a1 + ooff, b1 + ooff, 256);
#pragma unroll
    for (int o = 32; o > 0; o >>= 1) part += __shfl_down(part, o, 64);
    if ((threadIdx.x & 63) == 0) atomicAdd(acc, (double)part);
}

// ---- L1..L4, all 64x32 tiles: 32+8+2+1 = 43 tiles/image = 2064 waves (516 blocks) ----
__global__ __launch_bounds__(256, 4) void ssim_rest_kernel(
    const float* __restrict__ a1, const float* __restrict__ b1,
    const float* __restrict__ a2, const float* __restrict__ b2,
    const float* __restrict__ a3, const float* __restrict__ b3,
    const float* __restrict__ a4, const float* __restrict__ b4,
    double* __restrict__ acc, GW gw)
{
    __shared__ float4 rbs[4][80];
    const int wid = threadIdx.x >> 6;
    const int w = blockIdx.x * 4 + wid;
    const int img = w / 43;
    const int r = w - img * 43;
    int lvl, tx, ty;
    if (r < 32)      { lvl = 1; tx = r & 3;  ty = r >> 2; }                // 4x8
    else if (r < 40) { lvl = 2; int s = r - 32; tx = s & 1; ty = s >> 1; } // 2x4
    else if (r < 42) { lvl = 3; tx = 0; ty = r - 40; }                     // 1x2
    else             { lvl = 4; tx = 0; ty = 0; }                          // 1x1
    const int W = 512 >> lvl;
    const float* p1; const float* p2;
    switch (lvl) {
      case 1:  p1 = a1; p2 = b1; break;
      case 2:  p1 = a2; p2 = b2; break;
      case 3:  p1 = a3; p2 = b3; break;
      default: p1 = a4; p2 = b4; break;
    }
    const size_t off = (size_t)img * W * W;

    float part = ssim_wave_tile<false>(p1 + off, p2 + off, W, tx * 64, ty * 32,
                                       gw, rbs[wid], nullptr, nullptr, 0);
#pragma unroll
    for (int o = 32; o > 0; o >>= 1) part += __shfl_down(part, o, 64);
    if ((threadIdx.x & 63) == 0) atomicAdd(acc + lvl, (double)part);
}

// ---- pool L1 -> L2/L3/L4. Grid (16, 96). ----
__global__ __launch_bounds__(256) void pool_rest_kernel(
    const float* __restrict__ a1, const float* __restrict__ b1,
    float* __restrict__ a2, float* __restrict__ b2,
    float* __restrict__ a3, float* __restrict__ b3,
    float* __restrict__ a4, float* __restrict__ b4)
{
    __shared__ float l2[32][33];
    __shared__ float l3[16][17];
    const int tid = threadIdx.x;
    const int im = blockIdx.y;
    const int tb = blockIdx.x;
    const int tx = tb & 3, ty = tb >> 2;
    const bool second = im >= 48;
    const int ii = second ? im - 48 : im;
    const float* src = (second ? b1 : a1) + (size_t)ii * 256 * 256;
    float* o2 = (second ? b2 : a2) + (size_t)ii * 128 * 128;
    float* o3 = (second ? b3 : a3) + (size_t)ii * 64 * 64;
    float* o4 = (second ? b4 : a4) + (size_t)ii * 32 * 32;
    const int X0 = tx * 64, Y0 = ty * 64;

#pragma unroll
    for (int k = 0; k < 2; ++k) {
        int idx = tid + k * 256;
        int xp = idx & 15;
        int yo = idx >> 4;
        const float* rp = src + (size_t)(Y0 + 2 * yo) * 256 + (X0 + 4 * xp);
        float4 r0 = *(const float4*)rp;
        float4 r1 = *(const float4*)(rp + 256);
        float v0 = (r0.x + r0.y + r1.x + r1.y) * 0.25f;
        float v1 = (r0.z + r0.w + r1.z + r1.w) * 0.25f;
        l2[yo][2 * xp]     = v0;
        l2[yo][2 * xp + 1] = v1;
        float2* op = (float2*)(o2 + (size_t)((Y0 >> 1) + yo) * 128 + ((X0 >> 1) + 2 * xp));
        *op = make_float2(v0, v1);
    }
    __syncthreads();
    {
        int xo = tid & 15, yo = tid >> 4;
        if (yo < 16) {
            float v = (l2[2*yo][2*xo] + l2[2*yo][2*xo+1] +
                       l2[2*yo+1][2*xo] + l2[2*yo+1][2*xo+1]) * 0.25f;
            l3[yo][xo] = v;
            o3[(size_t)((Y0 >> 2) + yo) * 64 + ((X0 >> 2) + xo)] = v;
        }
    }
    __syncthreads();
    if (tid < 64) {
        int xo = tid & 7, yo = tid >> 3;
        float v = (l3[2*yo][2*xo] + l3[2*yo][2*xo+1] +
                   l3[2*yo+1][2*xo] + l3[2*yo+1][2*xo+1]) * 0.25f;
        o4[(size_t)((Y0 >> 3) + yo) * 32 + ((X0 >> 3) + xo)] = v;
    }
}

__global__ void final_kernel(const double* __restrict__ acc, float* __restrict__ out)
{
    double loss = 0.0;
#pragma unroll
    for (int l = 0; l < 5; ++l) {
        double cnt = 48.0 * (double)(512 >> l) * (double)(512 >> l);
        loss += 1.0 - acc[l] / cnt;
    }
    out[0] = (float)loss;
}

extern "C" void kernel_launch(void* const* d_in, const int* in_sizes, int n_in,
                              void* d_out, int out_size, void* d_ws, size_t ws_size,
                              hipStream_t stream)
{
    const float* img1 = (const float*)d_in[0];
    const float* img2 = (const float*)d_in[1];
    float* out = (float*)d_out;

    // 1D gaussian (sigma=1.5, k=11), matches reference construction
    GW gw;
    double gs[WIN], sum = 0.0;
    for (int i = 0; i < WIN; ++i) {
        double ax = (double)i - 5.0;
        gs[i] = exp(-(ax * ax) / 4.5);
        sum += gs[i];
    }
    for (int i = 0; i < WIN; ++i) gw.g[i] = (float)(gs[i] / sum);

    // workspace: 64B header (5 double acc), then pyramid
    double* acc = (double*)d_ws;
    float* base = (float*)((char*)d_ws + 64);
    const size_t n1 = 48ull * 256 * 256;
    const size_t n2 = 48ull * 128 * 128;
    const size_t n3 = 48ull * 64 * 64;
    const size_t n4 = 48ull * 32 * 32;
    float* a1 = base;      float* b1 = a1 + n1;
    float* a2 = b1 + n1;   float* b2 = a2 + n2;
    float* a3 = b2 + n2;   float* b3 = a3 + n3;
    float* a4 = b3 + n3;   float* b4 = a4 + n4;

    hipMemsetAsync(acc, 0, 5 * sizeof(double), stream);

    hipLaunchKernelGGL(ssim_l0_kernel, dim3(1536), dim3(256), 0, stream,
                       img1, img2, a1, b1, acc, gw);

    hipLaunchKernelGGL(pool_rest_kernel, dim3(16, 96), dim3(256), 0, stream,
                       a1, b1, a2, b2, a3, b3, a4, b4);

    hipLaunchKernelGGL(ssim_rest_kernel, dim3(516), dim3(256), 0, stream,
                       a1, b1, a2, b2, a3, b3, a4, b4, acc, gw);

    hipLaunchKernelGGL(final_kernel, dim3(1), dim3(1), 0, stream, acc, out);
}

// Round 10
// 336.480 us; speedup vs baseline: 1.0453x; 1.0453x over previous
//
#include <hip/hip_runtime.h>
#include <math.h>

#define WIN 11
#define PAD 5

typedef float v2f __attribute__((ext_vector_type(2)));

struct GW { float g[WIN]; };

// ---------------------------------------------------------------------------
// Wave-autonomous SSIM tile, DOUBLE-ROW STATIC-RING, INLINE-BODY edition.
// Compiler fact (4x confirmed): local arrays passed across ANY function /
// lambda / macro boundary (R8 ref-param, R9 lambda-capture, R7 macro) are
// lowered to scratch (SROA fails): WRITE_SIZE 170-200MB, dur +65%. Arrays
// written INLINE in the unrolled loop body with induction-variable indices
// stay in VGPRs (R0/R2/R3/R4/R5, WRITE 24.8MB). So the step body below is
// written out inline, twice (main blocks + tail) - deliberately.
// Why this structure: DS-pipe model. Per CU at ~10 resident waves, R5's
// 13 DS ops/row ~ 660 DS-pipe cyc per 1100-cyc row (R3's float4-per-row was
// fully saturated - why it was flat despite the VALU cut). One step = TWO
// rows: 11 ds_read_b128 + 2 ds_write per 2 rows = DS per row HALVED (~30%
// pipe occupancy) -> VALU becomes the binding constraint.
//   - branchless 2-row-ahead prefetch (R5: uniform vmcnt)
//   - LDS float4 (p0,q0,p1,q1) per column
//   - packed H-conv of both rows per tap (transient v2f only - R3/R5 safe)
//   - scalar V-conv ring float[12]: slot s holds output o == s (mod 12);
//     step d: row 2d taps w0=(2d-s) mod 12 (if <=10), row 2d+1 taps w0+1
//     (if <=10); slots (2d+2)%12,(2d+3)%12 emit outputs 2d-10, 2d-9, zero.
//     Startup garbage taps land in slots that are zeroed before their first
//     real tap (math 3x verified on HW: R7/R8/R9 absmax 0.0).
//   - 21 steps = rows 0..41: 3 blocks of 6 (phase period) + 3-step tail.
// Tripwire: WRITE_SIZE ~24.8MB / FETCH ~78MB; any growth = scratch = revert.
// EMIT: L0 pools rows (2d-1, 2d) into L1 at steps with 6 <= 2d <= 36.
// ---------------------------------------------------------------------------
template<bool EMIT>
__device__ __forceinline__ float ssim_wave_tile(
    const float* __restrict__ p1, const float* __restrict__ p2,
    int W, int X0, int Y0, const GW& gw, float4* __restrict__ rb,
    float* __restrict__ o1a, float* __restrict__ o1b, int Wout)
{
    const int lane = threadIdx.x & 63;
    const int gx = X0 + lane;
    const bool cval = gx < W;                              // false only for L4 lanes 32+
    const int hx   = (lane < 5) ? (X0 - 5 + lane) : (X0 + 59 + lane);
    const bool hval = (lane < 10) && ((unsigned)hx < (unsigned)W);
    const int hpos = (lane < 5) ? lane : (64 + lane);      // 0..4 | 69..73
    const int cpos = 5 + lane;
    const int gxc = cval ? gx : 0;                         // clamped main col
    const int hxc = hval ? hx : gxc;                       // masked halo -> own col
    const int wpos = (lane < 10) ? hpos : cpos;            // branchless halo write

    // loop-carried state: scalar arrays, touched ONLY inline in this scope
    float vMp[12], vSp[12], vMq[12], vSq[12];
#pragma unroll
    for (int k = 0; k < 12; ++k) { vMp[k] = 0.f; vSp[k] = 0.f; vMq[k] = 0.f; vSq[k] = 0.f; }

    float part = 0.f, pprev = 0.f, qprev = 0.f;
    float c0a, c0b, c0ah, c0bh, c1a, c1b, c1ah, c1bh;      // current rows 2d, 2d+1

    // scalar-in/scalar-out lambdas only (R5-proven safe; no array params)
    auto LOAD = [&](int t, float& oa, float& ob, float& oah, float& obh) {
        int y = Y0 - PAD + t;
        bool yin = (unsigned)y < (unsigned)W;
        const float* r1 = p1 + (size_t)(yin ? y : 0) * W;
        const float* r2 = p2 + (size_t)(yin ? y : 0) * W;
        float va = r1[gxc], vb = r2[gxc];
        float wa = r1[hxc], wb = r2[hxc];
        bool cv = yin && cval;
        bool hv = yin && hval;
        oa  = cv ? va : 0.f;
        ob  = cv ? vb : 0.f;
        oah = hv ? wa : 0.f;
        obh = hv ? wb : 0.f;
    };

    auto EMIT1 = [&](float Mp, float Mq, float Sp_, float Sq_, int o) {
        if ((unsigned)o < 32u) {
            bool yok = (unsigned)(Y0 + o) < (unsigned)W;   // false only for L4 tail
            const float C1v = 1e-4f, C2v = 9e-4f;
            float A = Mp * Mp, B = Mq * Mq;
            float ABp = A + B, ABm = A - B;
            float SSp = Sp_ + Sq_, SSm = Sp_ - Sq_;
            float n1 = fmaf(0.5f, ABm, C1v);         // 2*m12 + C1
            float n2 = fmaf(0.5f, SSm - ABm, C2v);   // 2*s12 + C2
            float e1 = fmaf(0.5f, ABp, C1v);         // m1^2+m2^2 + C1
            float e2 = fmaf(0.5f, SSp - ABp, C2v);   // s1+s2 + C2
            float val = (n1 * n2) * __builtin_amdgcn_rcpf(e1 * e2);
            part += (cval && yok) ? val : 0.f;
        }
    };

    LOAD(0, c0a, c0b, c0ah, c0bh);
    LOAD(1, c1a, c1b, c1ah, c1bh);

    // ---- main: 3 blocks x 6 steps (phase period 6); body INLINE ----------
#pragma unroll 1
    for (int blk = 0; blk < 3; ++blk) {
#pragma unroll
        for (int u = 0; u < 6; ++u) {
            const int d = blk * 6 + u;                     // runtime; ring uses u only

            // 1) prefetch rows 2d+2, 2d+3 (consumed next step)
            float n0, n1, n2, n3, n4, n5, n6, n7;
            LOAD(2 * d + 2, n0, n1, n2, n3);
            LOAD(2 * d + 3, n4, n5, n6, n7);

            // 2) LDS write rows (2d, 2d+1) packed as float4
            float p0  = c0a + c0b,   q0  = c0a - c0b;
            float ph0 = c0ah + c0bh, qh0 = c0ah - c0bh;
            float p1r = c1a + c1b,   q1r = c1a - c1b;
            float ph1 = c1ah + c1bh, qh1 = c1ah - c1bh;
            rb[cpos] = make_float4(p0, q0, p1r, q1r);
            rb[wpos] = (lane < 10) ? make_float4(ph0, qh0, ph1, qh1)
                                   : make_float4(p0, q0, p1r, q1r);
            __builtin_amdgcn_wave_barrier();   // writes -> reads (cross-lane RAW)

            // 3) H-conv of both rows from one b128 read per tap
            v2f hM0 = {0.f, 0.f}, hS0 = {0.f, 0.f};
            v2f hM1 = {0.f, 0.f}, hS1 = {0.f, 0.f};
#pragma unroll
            for (int j = 0; j < WIN; ++j) {
                float4 vv = rb[lane + j];
                v2f v0 = { vv.x, vv.y }, v1 = { vv.z, vv.w };
                v2f g2 = { gw.g[j], gw.g[j] };
                hM0 = __builtin_elementwise_fma(g2, v0, hM0);
                hS0 = __builtin_elementwise_fma(g2, v0 * v0, hS0);
                hM1 = __builtin_elementwise_fma(g2, v1, hM1);
                hS1 = __builtin_elementwise_fma(g2, v1 * v1, hS1);
            }
            __builtin_amdgcn_wave_barrier();   // reads -> next step's writes (WAR)
            float hp0 = hM0.x, hq0 = hM0.y, hpp0 = hS0.x, hqq0 = hS0.y;
            float hp1 = hM1.x, hq1 = hM1.y, hpp1 = hS1.x, hqq1 = hS1.y;

            // 4) V-conv static ring (indices fold: s,u both unrolled)
#pragma unroll
            for (int s = 0; s < 12; ++s) {
                const int w0v = ((2 * u - s) % 12 + 12) % 12;
                if (w0v <= 10) {
                    float g = gw.g[w0v];
                    vMp[s] = fmaf(g, hp0,  vMp[s]);
                    vSp[s] = fmaf(g, hpp0, vSp[s]);
                    vMq[s] = fmaf(g, hq0,  vMq[s]);
                    vSq[s] = fmaf(g, hqq0, vSq[s]);
                }
                const int w1v = (w0v + 1) % 12;
                if (w1v <= 10) {
                    float g = gw.g[w1v];
                    vMp[s] = fmaf(g, hp1,  vMp[s]);
                    vSp[s] = fmaf(g, hpp1, vSp[s]);
                    vMq[s] = fmaf(g, hq1,  vMq[s]);
                    vSq[s] = fmaf(g, hqq1, vSq[s]);
                }
            }

            // 5) emit outputs o = 2d-10, 2d-9; zero their slots
            {
                const int s0 = (2 * u + 2) % 12;
                const int s1 = (2 * u + 3) % 12;
                EMIT1(vMp[s0], vMq[s0], vSp[s0], vSq[s0], 2 * d - 10);
                EMIT1(vMp[s1], vMq[s1], vSp[s1], vSq[s1], 2 * d - 9);
                vMp[s0] = 0.f; vSp[s0] = 0.f; vMq[s0] = 0.f; vSq[s0] = 0.f;
                vMp[s1] = 0.f; vSp[s1] = 0.f; vMq[s1] = 0.f; vSq[s1] = 0.f;
            }

            // 6) L0 pooling of image rows (2d-1, 2d) -> L1
            if (EMIT) {
                int r_ = 2 * d;
                if (r_ >= 6 && r_ <= 36) {
                    float sp_ = p0 + pprev, sq_ = q0 + qprev;
                    float sp2 = sp_ + __shfl_down(sp_, 1, 64);
                    float sq2 = sq_ + __shfl_down(sq_, 1, 64);
                    if ((lane & 1) == 0) {
                        float P = sp2 * 0.25f, Q = sq2 * 0.25f;
                        int yo = d - 3;
                        size_t oo = (size_t)((Y0 >> 1) + yo) * Wout
                                  + ((X0 >> 1) + (lane >> 1));
                        o1a[oo] = (P + Q) * 0.5f;
                        o1b[oo] = (P - Q) * 0.5f;
                    }
                }
                pprev = p1r; qprev = q1r;
            }

            // 7) rotate prefetch regs
            c0a = n0; c0b = n1; c0ah = n2; c0bh = n3;
            c1a = n4; c1b = n5; c1ah = n6; c1bh = n7;

            __builtin_amdgcn_sched_barrier(0);   // pin step boundary
        }
    }

    // ---- tail: steps d = 18..20 (u = 0..2), body duplicated inline -------
#pragma unroll
    for (int u = 0; u < 3; ++u) {
        const int d = 18 + u;

        float n0, n1, n2, n3, n4, n5, n6, n7;
        LOAD(2 * d + 2, n0, n1, n2, n3);
        LOAD(2 * d + 3, n4, n5, n6, n7);

        float p0  = c0a + c0b,   q0  = c0a - c0b;
        float ph0 = c0ah + c0bh, qh0 = c0ah - c0bh;
        float p1r = c1a + c1b,   q1r = c1a - c1b;
        float ph1 = c1ah + c1bh, qh1 = c1ah - c1bh;
        rb[cpos] = make_float4(p0, q0, p1r, q1r);
        rb[wpos] = (lane < 10) ? make_float4(ph0, qh0, ph1, qh1)
                               : make_float4(p0, q0, p1r, q1r);
        __builtin_amdgcn_wave_barrier();

        v2f hM0 = {0.f, 0.f}, hS0 = {0.f, 0.f};
        v2f hM1 = {0.f, 0.f}, hS1 = {0.f, 0.f};
#pragma unroll
        for (int j = 0; j < WIN; ++j) {
            float4 vv = rb[lane + j];
            v2f v0 = { vv.x, vv.y }, v1 = { vv.z, vv.w };
            v2f g2 = { gw.g[j], gw.g[j] };
            hM0 = __builtin_elementwise_fma(g2, v0, hM0);
            hS0 = __builtin_elementwise_fma(g2, v0 * v0, hS0);
            hM1 = __builtin_elementwise_fma(g2, v1, hM1);
            hS1 = __builtin_elementwise_fma(g2, v1 * v1, hS1);
        }
        __builtin_amdgcn_wave_barrier();
        float hp0 = hM0.x, hq0 = hM0.y, hpp0 = hS0.x, hqq0 = hS0.y;
        float hp1 = hM1.x, hq1 = hM1.y, hpp1 = hS1.x, hqq1 = hS1.y;

#pragma unroll
        for (int s = 0; s < 12; ++s) {
            const int w0v = ((2 * u - s) % 12 + 12) % 12;
            if (w0v <= 10) {
                float g = gw.g[w0v];
                vMp[s] = fmaf(g, hp0,  vMp[s]);
                vSp[s] = fmaf(g, hpp0, vSp[s]);
                vMq[s] = fmaf(g, hq0,  vMq[s]);
                vSq[s] = fmaf(g, hqq0, vSq[s]);
            }
            const int w1v = (w0v + 1) % 12;
            if (w1v <= 10) {
                float g = gw.g[w1v];
                vMp[s] = fmaf(g, hp1,  vMp[s]);
                vSp[s] = fmaf(g, hpp1, vSp[s]);
                vMq[s] = fmaf(g, hq1,  vMq[s]);
                vSq[s] = fmaf(g, hqq1, vSq[s]);
            }
        }

        {
            const int s0 = (2 * u + 2) % 12;
            const int s1 = (2 * u + 3) % 12;
            EMIT1(vMp[s0], vMq[s0], vSp[s0], vSq[s0], 2 * d - 10);
            EMIT1(vMp[s1], vMq[s1], vSp[s1], vSq[s1], 2 * d - 9);
            vMp[s0] = 0.f; vSp[s0] = 0.f; vMq[s0] = 0.f; vSq[s0] = 0.f;
            vMp[s1] = 0.f; vSp[s1] = 0.f; vMq[s1] = 0.f; vSq[s1] = 0.f;
        }

        if (EMIT) {
            int r_ = 2 * d;
            if (r_ >= 6 && r_ <= 36) {
                float sp_ = p0 + pprev, sq_ = q0 + qprev;
                float sp2 = sp_ + __shfl_down(sp_, 1, 64);
                float sq2 = sq_ + __shfl_down(sq_, 1, 64);
                if ((lane & 1) == 0) {
                    float P = sp2 * 0.25f, Q = sq2 * 0.25f;
                    int yo = d - 3;
                    size_t oo = (size_t)((Y0 >> 1) + yo) * Wout
                              + ((X0 >> 1) + (lane >> 1));
                    o1a[oo] = (P + Q) * 0.5f;
                    o1b[oo] = (P - Q) * 0.5f;
                }
            }
            pprev = p1r; qprev = q1r;
        }

        c0a = n0; c0b = n1; c0ah = n2; c0bh = n3;
        c1a = n4; c1b = n5; c1ah = n6; c1bh = n7;

        __builtin_amdgcn_sched_barrier(0);
    }

    return part;
}

// ---- L0: 8x16 tiles (64x32) x 48 images = 6144 waves (1536 blocks); emits L1 ----
__global__ __launch_bounds__(256, 4) void ssim_l0_kernel(
    const float* __restrict__ i1, const float* __restrict__ i2,
    float* __restrict__ a1, float* __restrict__ b1,
    double* __restrict__ acc, GW gw)
{
    __shared__ float4 rbs[4][80];
    const int wid = threadIdx.x >> 6;
    const int w = blockIdx.x * 4 + wid;
    const int img = w >> 7;                 // 128 tiles per image
    const int tt = w & 127;
    const int tx = tt & 7, ty = tt >> 3;    // 8 cols x 16 rows
    const size_t off  = (size_t)img * 512 * 512;
    const size_t ooff = (size_t)img * 256 * 256;

    float part = ssim_wave_tile<true>(i1 + off, i2 + off, 512, tx * 64, ty * 32,
                                      gw, rbs[wid], a1 + ooff, b1 + ooff, 256);
#pragma unroll
    for (int o = 32; o > 0; o >>= 1) part += __shfl_down(part, o, 64);
    if ((threadIdx.x & 63) == 0) atomicAdd(acc, (double)part);
}

// ---- L1..L4, all 64x32 tiles: 32+8+2+1 = 43 tiles/image = 2064 waves (516 blocks) ----
__global__ __launch_bounds__(256, 4) void ssim_rest_kernel(
    const float* __restrict__ a1, const float* __restrict__ b1,
    const float* __restrict__ a2, const float* __restrict__ b2,
    const float* __restrict__ a3, const float* __restrict__ b3,
    const float* __restrict__ a4, const float* __restrict__ b4,
    double* __restrict__ acc, GW gw)
{
    __shared__ float4 rbs[4][80];
    const int wid = threadIdx.x >> 6;
    const int w = blockIdx.x * 4 + wid;
    const int img = w / 43;
    const int r = w - img * 43;
    int lvl, tx, ty;
    if (r < 32)      { lvl = 1; tx = r & 3;  ty = r >> 2; }                // 4x8
    else if (r < 40) { lvl = 2; int s = r - 32; tx = s & 1; ty = s >> 1; } // 2x4
    else if (r < 42) { lvl = 3; tx = 0; ty = r - 40; }                     // 1x2
    else             { lvl = 4; tx = 0; ty = 0; }                          // 1x1
    const int W = 512 >> lvl;
    const float* p1; const float* p2;
    switch (lvl) {
      case 1:  p1 = a1; p2 = b1; break;
      case 2:  p1 = a2; p2 = b2; break;
      case 3:  p1 = a3; p2 = b3; break;
      default: p1 = a4; p2 = b4; break;
    }
    const size_t off = (size_t)img * W * W;

    float part = ssim_wave_tile<false>(p1 + off, p2 + off, W, tx * 64, ty * 32,
                                       gw, rbs[wid], nullptr, nullptr, 0);
#pragma unroll
    for (int o = 32; o > 0; o >>= 1) part += __shfl_down(part, o, 64);
    if ((threadIdx.x & 63) == 0) atomicAdd(acc + lvl, (double)part);
}

// ---- pool L1 -> L2/L3/L4. Grid (16, 96). ----
__global__ __launch_bounds__(256) void pool_rest_kernel(
    const float* __restrict__ a1, const float* __restrict__ b1,
    float* __restrict__ a2, float* __restrict__ b2,
    float* __restrict__ a3, float* __restrict__ b3,
    float* __restrict__ a4, float* __restrict__ b4)
{
    __shared__ float l2[32][33];
    __shared__ float l3[16][17];
    const int tid = threadIdx.x;
    const int im = blockIdx.y;
    const int tb = blockIdx.x;
    const int tx = tb & 3, ty = tb >> 2;
    const bool second = im >= 48;
    const int ii = second ? im - 48 : im;
    const float* src = (second ? b1 : a1) + (size_t)ii * 256 * 256;
    float* o2 = (second ? b2 : a2) + (size_t)ii * 128 * 128;
    float* o3 = (second ? b3 : a3) + (size_t)ii * 64 * 64;
    float* o4 = (second ? b4 : a4) + (size_t)ii * 32 * 32;
    const int X0 = tx * 64, Y0 = ty * 64;

#pragma unroll
    for (int k = 0; k < 2; ++k) {
        int idx = tid + k * 256;
        int xp = idx & 15;
        int yo = idx >> 4;
        const float* rp = src + (size_t)(Y0 + 2 * yo) * 256 + (X0 + 4 * xp);
        float4 r0 = *(const float4*)rp;
        float4 r1 = *(const float4*)(rp + 256);
        float v0 = (r0.x + r0.y + r1.x + r1.y) * 0.25f;
        float v1 = (r0.z + r0.w + r1.z + r1.w) * 0.25f;
        l2[yo][2 * xp]     = v0;
        l2[yo][2 * xp + 1] = v1;
        float2* op = (float2*)(o2 + (size_t)((Y0 >> 1) + yo) * 128 + ((X0 >> 1) + 2 * xp));
        *op = make_float2(v0, v1);
    }
    __syncthreads();
    {
        int xo = tid & 15, yo = tid >> 4;
        if (yo < 16) {
            float v = (l2[2*yo][2*xo] + l2[2*yo][2*xo+1] +
                       l2[2*yo+1][2*xo] + l2[2*yo+1][2*xo+1]) * 0.25f;
            l3[yo][xo] = v;
            o3[(size_t)((Y0 >> 2) + yo) * 64 + ((X0 >> 2) + xo)] = v;
        }
    }
    __syncthreads();
    if (tid < 64) {
        int xo = tid & 7, yo = tid >> 3;
        float v = (l3[2*yo][2*xo] + l3[2*yo][2*xo+1] +
                   l3[2*yo+1][2*xo] + l3[2*yo+1][2*xo+1]) * 0.25f;
        o4[(size_t)((Y0 >> 3) + yo) * 32 + ((X0 >> 3) + xo)] = v;
    }
}

__global__ void final_kernel(const double* __restrict__ acc, float* __restrict__ out)
{
    double loss = 0.0;
#pragma unroll
    for (int l = 0; l < 5; ++l) {
        double cnt = 48.0 * (double)(512 >> l) * (double)(512 >> l);
        loss += 1.0 - acc[l] / cnt;
    }
    out[0] = (float)loss;
}

extern "C" void kernel_launch(void* const* d_in, const int* in_sizes, int n_in,
                              void* d_out, int out_size, void* d_ws, size_t ws_size,
                              hipStream_t stream)
{
    const float* img1 = (const float*)d_in[0];
    const float* img2 = (const float*)d_in[1];
    float* out = (float*)d_out;

    // 1D gaussian (sigma=1.5, k=11), matches reference construction
    GW gw;
    double gs[WIN], sum = 0.0;
    for (int i = 0; i < WIN; ++i) {
        double ax = (double)i - 5.0;
        gs[i] = exp(-(ax * ax) / 4.5);
        sum += gs[i];
    }
    for (int i = 0; i < WIN; ++i) gw.g[i] = (float)(gs[i] / sum);

    // workspace: 64B header (5 double acc), then pyramid
    double* acc = (double*)d_ws;
    float* base = (float*)((char*)d_ws + 64);
    const size_t n1 = 48ull * 256 * 256;
    const size_t n2 = 48ull * 128 * 128;
    const size_t n3 = 48ull * 64 * 64;
    const size_t n4 = 48ull * 32 * 32;
    float* a1 = base;      float* b1 = a1 + n1;
    float* a2 = b1 + n1;   float* b2 = a2 + n2;
    float* a3 = b2 + n2;   float* b3 = a3 + n3;
    float* a4 = b3 + n3;   float* b4 = a4 + n4;

    hipMemsetAsync(acc, 0, 5 * sizeof(double), stream);

    hipLaunchKernelGGL(ssim_l0_kernel, dim3(1536), dim3(256), 0, stream,
                       img1, img2, a1, b1, acc, gw);

    hipLaunchKernelGGL(pool_rest_kernel, dim3(16, 96), dim3(256), 0, stream,
                       a1, b1, a2, b2, a3, b3, a4, b4);

    hipLaunchKernelGGL(ssim_rest_kernel, dim3(516), dim3(256), 0, stream,
                       a1, b1, a2, b2, a3, b3, a4, b4, acc, gw);

    hipLaunchKernelGGL(final_kernel, dim3(1), dim3(1), 0, stream, acc, out);
}

// Round 12
// 266.268 us; speedup vs baseline: 1.3209x; 1.2637x over previous
//
#include <hip/hip_runtime.h>
#include <math.h>

#define WIN 11
#define PAD 5

typedef float v2f __attribute__((ext_vector_type(2)));

struct GW { float g[WIN]; };

// ---------------------------------------------------------------------------
// R5 tile (best verified: VGPR 56, zero scratch) + IN-TILE PYRAMID CASCADE.
// R11 lesson: hipLaunchCooperativeKernel silently fails under the harness's
// graph capture (out stayed 0) -> no grid.sync available. But the pyramid is
// TILE-LOCAL (avg_pool2 is non-overlapping 2x2; every tile origin is even at
// every level), so the L0 kernel emits L1 AND L2/L3/L4 itself: the pooled
// (P,Q) row on even lanes is cascaded with prev-row registers + shfl_down
// (2/4/8) - no extra LDS, ~6 loop-carried scalars. This deletes the pool
// dispatch and its ~33MB HBM round-trip. 5 dispatches -> 3.
// DO NOT restructure the conv core: the double-row/packed-accumulator family
// (R1,R7-R10) spills to scratch under every delivery mechanism tried (macro,
// template, lambda, inline): 119-200MB WRITE_SIZE, +65% dur. Scalar float[11]
// ring accumulators indexed by unrolled u, inline in this exact shape, is
// the only form hipcc keeps in VGPRs (5x confirmed).
// ---------------------------------------------------------------------------
template<bool EMIT>
__device__ __forceinline__ float ssim_wave_tile(
    const float* __restrict__ p1, const float* __restrict__ p2,
    int W, int X0, int Y0, const GW& gw, float2* __restrict__ rb,
    float* __restrict__ o1a, float* __restrict__ o1b,
    float* __restrict__ o2a, float* __restrict__ o2b,
    float* __restrict__ o3a, float* __restrict__ o3b,
    float* __restrict__ o4a, float* __restrict__ o4b)
{
    const int TH = 32;
    const int lane = threadIdx.x & 63;
    const int gx = X0 + lane;
    const bool cval = gx < W;                              // false only for L4 lanes 32+
    const int hx   = (lane < 5) ? (X0 - 5 + lane) : (X0 + 59 + lane);
    const bool hval = (lane < 10) && ((unsigned)hx < (unsigned)W);
    const int hpos = (lane < 5) ? lane : (64 + lane);      // 0..4 | 69..73
    const int cpos = 5 + lane;
    const int gxc = cval ? gx : 0;                         // clamped main col
    const int hxc = hval ? hx : gxc;                       // masked halo -> own col
    const int wpos = (lane < 10) ? hpos : cpos;            // branchless halo write

    float vMp[11], vSp[11], vMq[11], vSq[11];
#pragma unroll
    for (int k = 0; k < 11; ++k) { vMp[k] = 0.f; vSp[k] = 0.f; vMq[k] = 0.f; vSq[k] = 0.f; }

    float part = 0.f;
    float pprev = 0.f, qprev = 0.f;
    // pyramid cascade carry (P,Q of the previous row at each level)
    float pv1P = 0.f, pv1Q = 0.f, pv2P = 0.f, pv2Q = 0.f, pv3P = 0.f, pv3Q = 0.f;

    // BRANCHLESS load: 4 unconditional global_load_dword per row, results
    // zero-selected. Statically uniform load count -> counted vmcnt.
    auto LOAD = [&](int t, float& oa, float& ob, float& oah, float& obh) {
        int y = Y0 - PAD + t;
        bool yin = (unsigned)y < (unsigned)W;
        const float* r1 = p1 + (size_t)(yin ? y : 0) * W;
        const float* r2 = p2 + (size_t)(yin ? y : 0) * W;
        float va = r1[gxc], vb = r2[gxc];
        float wa = r1[hxc], wb = r2[hxc];
        bool cv = yin && cval;
        bool hv = yin && hval;
        oa  = cv ? va : 0.f;
        ob  = cv ? vb : 0.f;
        oah = hv ? wa : 0.f;
        obh = hv ? wb : 0.f;
    };

    // depth-2 prefetch pipeline: row t in (a0..), t+1 in (a1..)
    float a0, b0, ah0, bh0;
    float a1, b1, ah1, bh1;
    LOAD(0, a0, b0, ah0, bh0);
    LOAD(1, a1, b1, ah1, bh1);

#pragma unroll 1
    for (int blk = 0; blk < 4; ++blk) {
#pragma unroll
        for (int u = 0; u < 11; ++u) {
            const int t = blk * 11 + u;        // u compile-time, blk runtime

            // issue row t+2 now; consumed two full row-bodies from now
            float a2, b2, ah2, bh2;
            LOAD(t + 2, a2, b2, ah2, bh2);

            float p = a0 + b0, q = a0 - b0;
            float ph = ah0 + bh0, qh = ah0 - bh0;
            rb[cpos] = make_float2(p, q);
            // lanes<10: halo slot; lanes>=10: harmless same-value rewrite
            rb[wpos] = (lane < 10) ? make_float2(ph, qh) : make_float2(p, q);
            __builtin_amdgcn_wave_barrier();   // writes -> reads (cross-lane RAW)

            v2f hM = {0.f, 0.f}, hS = {0.f, 0.f};
#pragma unroll
            for (int j = 0; j < WIN; ++j) {
                float2 v = rb[lane + j];
                v2f vm = { v.x, v.y };
                v2f g2 = { gw.g[j], gw.g[j] };
                hM = __builtin_elementwise_fma(g2, vm, hM);
                hS = __builtin_elementwise_fma(g2, vm * vm, hS);
            }
            __builtin_amdgcn_wave_barrier();   // reads -> next row's writes (WAR)
            float hp = hM.x, hq = hM.y, hpp = hS.x, hqq = hS.y;

            // V-conv static ring: slot s, row t: weight g[10 - ((s-t) mod 11)]
#pragma unroll
            for (int s = 0; s < 11; ++s) {
                const int widx = 10 - ((s - u + 11) % 11);
                float g = gw.g[widx];
                vMp[s] = fmaf(g, hp,  vMp[s]);
                vSp[s] = fmaf(g, hpp, vSp[s]);
                vMq[s] = fmaf(g, hq,  vMq[s]);
                vSq[s] = fmaf(g, hqq, vSq[s]);
            }

            if (EMIT) {
                if (t >= 6 && t <= TH + 4 && (t & 1) == 0) {   // pool rows (t-1, t)
                    float sp_ = p + pprev, sq_ = q + qprev;
                    float sp2 = sp_ + __shfl_down(sp_, 1, 64);
                    float sq2 = sq_ + __shfl_down(sq_, 1, 64);
                    float P = sp2 * 0.25f, Q = sq2 * 0.25f;    // L1 (even lanes)
                    int yo = (t - 6) >> 1;                     // L1 row 0..15
                    if ((lane & 1) == 0) {
                        size_t oo = (size_t)((Y0 >> 1) + yo) * 256 + ((X0 >> 1) + (lane >> 1));
                        o1a[oo] = (P + Q) * 0.5f;
                        o1b[oo] = (P - Q) * 0.5f;
                    }
                    // ---- tile-local pyramid cascade (L2/L3/L4) ----
                    if (yo & 1) {
                        float p2s = P + pv1P, q2s = Q + pv1Q;
                        float P2 = (p2s + __shfl_down(p2s, 2, 64)) * 0.25f;  // lane%4==0
                        float Q2 = (q2s + __shfl_down(q2s, 2, 64)) * 0.25f;
                        int l2r = yo >> 1;                     // L2 row 0..7
                        if ((lane & 3) == 0) {
                            size_t oo = (size_t)((Y0 >> 2) + l2r) * 128 + ((X0 >> 2) + (lane >> 2));
                            o2a[oo] = (P2 + Q2) * 0.5f;
                            o2b[oo] = (P2 - Q2) * 0.5f;
                        }
                        if (l2r & 1) {
                            float p3s = P2 + pv2P, q3s = Q2 + pv2Q;
                            float P3 = (p3s + __shfl_down(p3s, 4, 64)) * 0.25f;  // lane%8==0
                            float Q3 = (q3s + __shfl_down(q3s, 4, 64)) * 0.25f;
                            int l3r = l2r >> 1;                // L3 row 0..3
                            if ((lane & 7) == 0) {
                                size_t oo = (size_t)((Y0 >> 3) + l3r) * 64 + ((X0 >> 3) + (lane >> 3));
                                o3a[oo] = (P3 + Q3) * 0.5f;
                                o3b[oo] = (P3 - Q3) * 0.5f;
                            }
                            if (l3r & 1) {
                                float p4s = P3 + pv3P, q4s = Q3 + pv3Q;
                                float P4 = (p4s + __shfl_down(p4s, 8, 64)) * 0.25f;  // lane%16==0
                                float Q4 = (q4s + __shfl_down(q4s, 8, 64)) * 0.25f;
                                int l4r = l3r >> 1;            // L4 row 0..1
                                if ((lane & 15) == 0) {
                                    size_t oo = (size_t)((Y0 >> 4) + l4r) * 32 + ((X0 >> 4) + (lane >> 4));
                                    o4a[oo] = (P4 + Q4) * 0.5f;
                                    o4b[oo] = (P4 - Q4) * 0.5f;
                                }
                            } else { pv3P = P3; pv3Q = Q3; }
                        } else { pv2P = P2; pv2Q = Q2; }
                    } else { pv1P = P; pv1Q = Q; }
                }
                pprev = p; qprev = q;
            }

            // slot u completes output o = t-10 this row (after its g[10] tap)
            {
                int o = t - 10;
                if ((unsigned)o < (unsigned)TH) {
                    bool yok = (unsigned)(Y0 + o) < (unsigned)W;   // false only for L4 tail
                    float Mp = vMp[u], Sp_ = vSp[u], Mq = vMq[u], Sq_ = vSq[u];
                    const float C1v = 1e-4f, C2v = 9e-4f;
                    float A = Mp * Mp, B = Mq * Mq;
                    float ABp = A + B, ABm = A - B;
                    float SSp = Sp_ + Sq_, SSm = Sp_ - Sq_;
                    float n1 = fmaf(0.5f, ABm, C1v);         // 2*m12 + C1
                    float n2 = fmaf(0.5f, SSm - ABm, C2v);   // 2*s12 + C2
                    float e1 = fmaf(0.5f, ABp, C1v);         // m1^2+m2^2 + C1
                    float e2 = fmaf(0.5f, SSp - ABp, C2v);   // s1+s2 + C2
                    float v = (n1 * n2) * __builtin_amdgcn_rcpf(e1 * e2);
                    part += (cval && yok) ? v : 0.f;
                }
                vMp[u] = 0.f; vSp[u] = 0.f; vMq[u] = 0.f; vSq[u] = 0.f;
            }

            // rotate prefetch pipeline
            a0 = a1; b0 = b1; ah0 = ah1; bh0 = bh1;
            a1 = a2; b1 = b2; ah1 = ah2; bh1 = bh2;

            // pin row boundary: no load hoisting / cross-row motion
            __builtin_amdgcn_sched_barrier(0);
        }
    }

    return part;
}

// ---- L0: 8x16 tiles (64x32) x 48 images = 6144 waves (1536 blocks);
//      emits the ENTIRE pyramid (L1..L4) tile-locally ----
__global__ __launch_bounds__(256, 4) void ssim_l0_kernel(
    const float* __restrict__ i1, const float* __restrict__ i2,
    float* __restrict__ a1, float* __restrict__ b1,
    float* __restrict__ a2, float* __restrict__ b2,
    float* __restrict__ a3, float* __restrict__ b3,
    float* __restrict__ a4, float* __restrict__ b4,
    double* __restrict__ acc, GW gw)
{
    __shared__ float2 rbs[4][80];
    const int wid = threadIdx.x >> 6;
    const int w = blockIdx.x * 4 + wid;
    const int img = w >> 7;                 // 128 tiles per image
    const int tt = w & 127;
    const int tx = tt & 7, ty = tt >> 3;    // 8 cols x 16 rows
    const size_t off  = (size_t)img * 512 * 512;

    float part = ssim_wave_tile<true>(
        i1 + off, i2 + off, 512, tx * 64, ty * 32, gw, rbs[wid],
        a1 + (size_t)img * 256 * 256, b1 + (size_t)img * 256 * 256,
        a2 + (size_t)img * 128 * 128, b2 + (size_t)img * 128 * 128,
        a3 + (size_t)img * 64 * 64,   b3 + (size_t)img * 64 * 64,
        a4 + (size_t)img * 32 * 32,   b4 + (size_t)img * 32 * 32);
#pragma unroll
    for (int o = 32; o > 0; o >>= 1) part += __shfl_down(part, o, 64);
    if ((threadIdx.x & 63) == 0) atomicAdd(acc, (double)part);
}

// ---- L1..L4, 64x32 tiles: 32+8+2+1 = 43/img = 2064 waves (516 blocks).
//      LAST-BLOCK-DONE pattern folds the final reduction in (no extra
//      dispatch, no grid barrier, deadlock-free regardless of residency). ----
__global__ __launch_bounds__(256, 4) void ssim_rest_kernel(
    const float* __restrict__ a1, const float* __restrict__ b1,
    const float* __restrict__ a2, const float* __restrict__ b2,
    const float* __restrict__ a3, const float* __restrict__ b3,
    const float* __restrict__ a4, const float* __restrict__ b4,
    double* __restrict__ acc, unsigned int* __restrict__ done,
    float* __restrict__ out, GW gw)
{
    __shared__ float2 rbs[4][80];
    const int wid = threadIdx.x >> 6;
    const int w = blockIdx.x * 4 + wid;
    const int img = w / 43;
    const int r = w - img * 43;
    int lvl, tx, ty;
    if (r < 32)      { lvl = 1; tx = r & 3;  ty = r >> 2; }                // 4x8
    else if (r < 40) { lvl = 2; int s = r - 32; tx = s & 1; ty = s >> 1; } // 2x4
    else if (r < 42) { lvl = 3; tx = 0; ty = r - 40; }                     // 1x2
    else             { lvl = 4; tx = 0; ty = 0; }                          // 1x1
    const int W = 512 >> lvl;
    const float* p1; const float* p2;
    switch (lvl) {
      case 1:  p1 = a1; p2 = b1; break;
      case 2:  p1 = a2; p2 = b2; break;
      case 3:  p1 = a3; p2 = b3; break;
      default: p1 = a4; p2 = b4; break;
    }
    const size_t off = (size_t)img * W * W;

    float part = ssim_wave_tile<false>(p1 + off, p2 + off, W, tx * 64, ty * 32,
                                       gw, rbs[wid], nullptr, nullptr,
                                       nullptr, nullptr, nullptr, nullptr,
                                       nullptr, nullptr);
#pragma unroll
    for (int o = 32; o > 0; o >>= 1) part += __shfl_down(part, o, 64);
    if ((threadIdx.x & 63) == 0) atomicAdd(acc + lvl, (double)part);

    // last block to finish computes the final loss (acc[0] from the previous
    // dispatch; acc[1..4] from this one - visible via release/acquire fences)
    __syncthreads();
    if (threadIdx.x == 0) {
        __threadfence();
        unsigned int prev = atomicAdd(done, 1u);
        if (prev == gridDim.x - 1) {
            __threadfence();
            double loss = 0.0;
#pragma unroll
            for (int l = 0; l < 5; ++l) {
                double cnt = 48.0 * (double)(512 >> l) * (double)(512 >> l);
                loss += 1.0 - acc[l] / cnt;
            }
            out[0] = (float)loss;
        }
    }
}

extern "C" void kernel_launch(void* const* d_in, const int* in_sizes, int n_in,
                              void* d_out, int out_size, void* d_ws, size_t ws_size,
                              hipStream_t stream)
{
    const float* img1 = (const float*)d_in[0];
    const float* img2 = (const float*)d_in[1];
    float* out = (float*)d_out;

    // 1D gaussian (sigma=1.5, k=11), matches reference construction
    GW gw;
    double gs[WIN], sum = 0.0;
    for (int i = 0; i < WIN; ++i) {
        double ax = (double)i - 5.0;
        gs[i] = exp(-(ax * ax) / 4.5);
        sum += gs[i];
    }
    for (int i = 0; i < WIN; ++i) gw.g[i] = (float)(gs[i] / sum);

    // workspace: 64B header (5 double acc @0, uint done-counter @40), pyramid after
    double* acc = (double*)d_ws;
    unsigned int* done = (unsigned int*)((char*)d_ws + 40);
    float* base = (float*)((char*)d_ws + 64);
    const size_t n1 = 48ull * 256 * 256;
    const size_t n2 = 48ull * 128 * 128;
    const size_t n3 = 48ull * 64 * 64;
    const size_t n4 = 48ull * 32 * 32;
    float* a1 = base;      float* b1 = a1 + n1;
    float* a2 = b1 + n1;   float* b2 = a2 + n2;
    float* a3 = b2 + n2;   float* b3 = a3 + n3;
    float* a4 = b3 + n3;   float* b4 = a4 + n4;

    hipMemsetAsync(d_ws, 0, 64, stream);   // acc[0..4] + done

    hipLaunchKernelGGL(ssim_l0_kernel, dim3(1536), dim3(256), 0, stream,
                       img1, img2, a1, b1, a2, b2, a3, b3, a4, b4, acc, gw);

    hipLaunchKernelGGL(ssim_rest_kernel, dim3(516), dim3(256), 0, stream,
                       a1, b1, a2, b2, a3, b3, a4, b4, acc, done, out, gw);
}